// Round 2
// 102.962 us; speedup vs baseline: 1.0233x; 1.0233x over previous
//
#include <hip/hip_runtime.h>
#include <hip/hip_fp16.h>
#include <math.h>

#define NMODES 64
#define SDIM   1024
#define BATCH  256
#define PDIM   4096
#define HDIM   128

typedef _Float16 half8  __attribute__((ext_vector_type(8)));
typedef _Float16 half4v __attribute__((ext_vector_type(4)));
typedef float    f32x4  __attribute__((ext_vector_type(4)));

// ws layout (bytes):
//   branch @ 0     : f16 [256][128]    (64 KB)
//   t3     @ 65536 : f16 [4096][128]   (1 MB)
#define WSB_BRANCH 0
#define WSB_T3     (BATCH * HDIM * 2)

// f16 LDS leading dim: 136 halves = 272 B rows -> lane stride 68 words,
// bank = 4*lm mod 32 -> 2-way alias only (free per m136). 144 would be 4-way.
#define LDW 136

union KMixSmem {
    struct {                       // trunk path (52.7 KB)
        _Float16 Ws[128 * LDW];    // staged weight tile (f16): W2 then W3
        _Float16 h1[32 * LDW];
        _Float16 h2[32 * LDW];
        float    feat[32][4];
    } tr;
    struct {                       // fourier/branch path (6.7 KB)
        float u0row[SDIM];
        float part[2][HDIM];
        float fr[HDIM];
        float hh[HDIM];
        float g2[HDIM];
    } fb;
};

// ---------------------------------------------------------------------------
// K1 (fused, 384 blocks x 256 thr):
//   blocks 0..127   : trunk MLP, 32 points each, L2/L3 via f16 MFMA -> t3 (f16)
//   blocks 128..383 : fourier (fma-angle + hw cos/sin) + branch MLP, 1 row each
// 3 blocks/CU resident (52.7 KB LDS) -> trunk+fourier co-scheduled, real TLP.
// ---------------------------------------------------------------------------
__global__ __launch_bounds__(256) void k_mix(
    const float* __restrict__ u0,
    const float* __restrict__ xv, const float* __restrict__ tv,
    const float* __restrict__ bw1, const float* __restrict__ bb1,
    const float* __restrict__ bw2, const float* __restrict__ bb2,
    const float* __restrict__ bw3, const float* __restrict__ bb3,
    const float* __restrict__ tw1, const float* __restrict__ tb1,
    const float* __restrict__ tw2, const float* __restrict__ tb2,
    const float* __restrict__ tw3, const float* __restrict__ tb3,
    __half* __restrict__ branch_out, __half* __restrict__ t3g) {
    __shared__ KMixSmem sm;
    const int t = threadIdx.x;

    if (blockIdx.x < 128) {
        // ================= trunk: 32 points, MFMA =================
        const int pbase = blockIdx.x * 32;

        // stage W2 -> LDS f16, fully coalesced (16 float4 / thread)
#pragma unroll
        for (int i = 0; i < 16; ++i) {
            int F = i * 256 + t;                       // float4 index 0..4095
            float4 wv = ((const float4*)tw2)[F];
            half4v h; h.x = (_Float16)wv.x; h.y = (_Float16)wv.y;
            h.z = (_Float16)wv.z; h.w = (_Float16)wv.w;
            *(half4v*)&sm.tr.Ws[(F >> 5) * LDW + (F & 31) * 4] = h;
        }
        if (t < 32) {
            int p = pbase + t;
            float x = xv[p], tt = tv[p];
            float qq = tt * tt - x * x;
            sm.tr.feat[t][0] = x;
            sm.tr.feat[t][1] = tt;
            sm.tr.feat[t][2] = (qq > 0.f) ? sqrtf(qq) : 0.f;
            sm.tr.feat[t][3] = (fabsf(x) <= tt) ? 1.f : 0.f;
        }
        __syncthreads();

        // L1: 4 -> 128 (f32 VALU), write h1 f16
        const int j = t & 127, pg = t >> 7;
        {
            float4 w1 = ((const float4*)tw1)[j];
            float b1 = tb1[j];
#pragma unroll
            for (int i = 0; i < 16; ++i) {
                int p = 2 * i + pg;                    // wave-uniform p -> LDS broadcast
                float4 f = *(const float4*)sm.tr.feat[p];
                float v = fmaf(w1.x, f.x, fmaf(w1.y, f.y,
                           fmaf(w1.z, f.z, fmaf(w1.w, f.w, b1))));
                sm.tr.h1[p * LDW + j] = (_Float16)fmaxf(v, 0.f);
            }
        }
        __syncthreads();

        const int lane = t & 63, w = t >> 6;
        const int lm = lane & 15, q = lane >> 4;
        const int mt = w & 1, nh = w >> 1;             // wave -> (m-tile, n-half)

        // L2 GEMM: h1(32x128) @ W2^T + tb2, relu -> h2 f16
        {
            f32x4 acc[4] = {f32x4{0,0,0,0}, f32x4{0,0,0,0},
                            f32x4{0,0,0,0}, f32x4{0,0,0,0}};
            const _Float16* aB = &sm.tr.h1[(mt * 16 + lm) * LDW + q * 8];
#pragma unroll
            for (int ks = 0; ks < 4; ++ks) {
                half8 af = *(const half8*)(aB + ks * 32);
#pragma unroll
                for (int n = 0; n < 4; ++n) {
                    half8 bf = *(const half8*)
                        &sm.tr.Ws[((nh * 4 + n) * 16 + lm) * LDW + q * 8 + ks * 32];
                    acc[n] = __builtin_amdgcn_mfma_f32_16x16x32_f16(af, bf, acc[n], 0, 0, 0);
                }
            }
            // C/D layout: col=lane&15, row=(lane>>4)*4+reg (m89-verified)
#pragma unroll
            for (int n = 0; n < 4; ++n) {
                int col = (nh * 4 + n) * 16 + lm;
                float b = tb2[col];
#pragma unroll
                for (int e = 0; e < 4; ++e)
                    sm.tr.h2[(mt * 16 + q * 4 + e) * LDW + col] =
                        (_Float16)fmaxf(acc[n][e] + b, 0.f);
            }
        }
        __syncthreads();                               // Ws consumed, h2 ready

        // stage W3 -> LDS f16
#pragma unroll
        for (int i = 0; i < 16; ++i) {
            int F = i * 256 + t;
            float4 wv = ((const float4*)tw3)[F];
            half4v h; h.x = (_Float16)wv.x; h.y = (_Float16)wv.y;
            h.z = (_Float16)wv.z; h.w = (_Float16)wv.w;
            *(half4v*)&sm.tr.Ws[(F >> 5) * LDW + (F & 31) * 4] = h;
        }
        __syncthreads();

        // L3 GEMM: h2 @ W3^T + tb3 -> t3 global f16
        {
            f32x4 acc[4] = {f32x4{0,0,0,0}, f32x4{0,0,0,0},
                            f32x4{0,0,0,0}, f32x4{0,0,0,0}};
            const _Float16* aB = &sm.tr.h2[(mt * 16 + lm) * LDW + q * 8];
#pragma unroll
            for (int ks = 0; ks < 4; ++ks) {
                half8 af = *(const half8*)(aB + ks * 32);
#pragma unroll
                for (int n = 0; n < 4; ++n) {
                    half8 bf = *(const half8*)
                        &sm.tr.Ws[((nh * 4 + n) * 16 + lm) * LDW + q * 8 + ks * 32];
                    acc[n] = __builtin_amdgcn_mfma_f32_16x16x32_f16(af, bf, acc[n], 0, 0, 0);
                }
            }
#pragma unroll
            for (int n = 0; n < 4; ++n) {
                int col = (nh * 4 + n) * 16 + lm;
                float b = tb3[col];
#pragma unroll
                for (int e = 0; e < 4; ++e) {
                    int p = pbase + mt * 16 + q * 4 + e;
                    t3g[(size_t)p * HDIM + col] = __float2half(acc[n][e] + b);
                }
            }
        }
        return;
    }

    // ================= fourier + branch MLP (1 row) =================
    const int row = blockIdx.x - 128;
    ((float4*)sm.fb.u0row)[t] = ((const float4*)(u0 + (size_t)row * SDIM))[t];
    __syncthreads();

    const int j = t & 127, sh = t >> 7;
    {
        // angle in REVOLUTIONS: rev(s) = k*s/1023 - k/2. Computed by fma from a
        // running float s (carried chain = one v_add), fract off-chain, then
        // hw v_cos/v_sin. fma abs err <= 64*2^-24 rev ~ 2.4e-5 rad.
        const int kmode = (j & 63) + 1;
        const float r  = (float)kmode * (1.0f / 1023.0f);
        const float a0 = -0.5f * (float)kmode;
        float sf = (float)(sh * 512);
        const float* up = sm.fb.u0row + sh * 512;
        float acc = 0.f;
        if (j < 64) {                                  // wave-uniform branch
#pragma unroll 8
            for (int s = 0; s < 512; ++s) {
                float a = fmaf(sf, r, a0);
                a -= floorf(a);
                acc = fmaf(__builtin_amdgcn_cosf(a), up[s], acc);
                sf += 1.0f;
            }
        } else {
#pragma unroll 8
            for (int s = 0; s < 512; ++s) {
                float a = fmaf(sf, r, a0);
                a -= floorf(a);
                acc = fmaf(__builtin_amdgcn_sinf(a), up[s], acc);
                sf += 1.0f;
            }
        }
        sm.fb.part[sh][j] = acc;
    }
    __syncthreads();
    if (t < 128)
        sm.fb.fr[j] = (sm.fb.part[0][j] + sm.fb.part[1][j]) * (1.0f / (float)SDIM);
    __syncthreads();

    // branch MLP (f32), one row; weights L2-hot across 256 blocks
    if (t < 128) {
        const float4* wp = (const float4*)(bw1 + (size_t)j * HDIM);
        float c0 = bb1[j];
        for (int i4 = 0; i4 < 32; ++i4) {
            float4 wv = wp[i4];
            float4 x0 = *(const float4*)&sm.fb.fr[i4 * 4];
            c0 += wv.x * x0.x + wv.y * x0.y + wv.z * x0.z + wv.w * x0.w;
        }
        sm.fb.hh[j] = fmaxf(c0, 0.f);
    }
    __syncthreads();
    if (t < 128) {
        const float4* wp = (const float4*)(bw2 + (size_t)j * HDIM);
        float c0 = bb2[j];
        for (int i4 = 0; i4 < 32; ++i4) {
            float4 wv = wp[i4];
            float4 x0 = *(const float4*)&sm.fb.hh[i4 * 4];
            c0 += wv.x * x0.x + wv.y * x0.y + wv.z * x0.z + wv.w * x0.w;
        }
        sm.fb.g2[j] = fmaxf(c0, 0.f);
    }
    __syncthreads();
    if (t < 128) {
        const float4* wp = (const float4*)(bw3 + (size_t)j * HDIM);
        float c0 = bb3[j];
        for (int i4 = 0; i4 < 32; ++i4) {
            float4 wv = wp[i4];
            float4 x0 = *(const float4*)&sm.fb.g2[i4 * 4];
            c0 += wv.x * x0.x + wv.y * x0.y + wv.z * x0.z + wv.w * x0.w;
        }
        branch_out[(size_t)row * HDIM + j] = __float2half(c0);
    }
}

// ---------------------------------------------------------------------------
// K2: final einsum via fp16 MFMA. out(256x4096) = br(256x128) @ t3^T * causal.
// 256 blocks (4 batch-tiles x 64 point-tiles of 64x64). LDH 144->136 (2-way
// bank alias instead of 4-way).
// ---------------------------------------------------------------------------
#define LDH 136
__global__ __launch_bounds__(256) void k_final(
    const __half* __restrict__ br_g, const __half* __restrict__ t3g,
    const float* __restrict__ xv, const float* __restrict__ tv,
    float* __restrict__ out) {
    __shared__ _Float16 brL[64 * LDH];
    __shared__ _Float16 ttL[64 * LDH];
    __shared__ float causL[64];

    const int t = threadIdx.x;
    const int rb = blockIdx.x >> 6;   // batch tile 0..3
    const int cb = blockIdx.x & 63;   // point tile 0..63

    if (t < 64) {
        int p = cb * 64 + t;
        float x = xv[p], tt = tv[p];
        causL[t] = (fabsf(x) <= tt) ? 1.f : 0.f;
    }

#pragma unroll
    for (int it = 0; it < 4; ++it) {
        int flat = t + 256 * it;
        int row = flat >> 4, c = flat & 15;
        *(float4*)&brL[row * LDH + c * 8] =
            *(const float4*)&br_g[(size_t)(rb * 64 + row) * HDIM + c * 8];
        *(float4*)&ttL[row * LDH + c * 8] =
            *(const float4*)&t3g[(size_t)(cb * 64 + row) * HDIM + c * 8];
    }
    __syncthreads();

    const int lane = t & 63;
    const int w = t >> 6;
    const int lm = lane & 15;
    const int q = lane >> 4;

    f32x4 acc[4] = {f32x4{0,0,0,0}, f32x4{0,0,0,0}, f32x4{0,0,0,0}, f32x4{0,0,0,0}};

    const _Float16* aBase = &brL[(16 * w + lm) * LDH + q * 8];
#pragma unroll
    for (int ks = 0; ks < 4; ++ks) {
        half8 af = *(const half8*)(aBase + ks * 32);
#pragma unroll
        for (int jt = 0; jt < 4; ++jt) {
            half8 bf = *(const half8*)&ttL[(16 * jt + lm) * LDH + q * 8 + ks * 32];
            acc[jt] = __builtin_amdgcn_mfma_f32_16x16x32_f16(af, bf, acc[jt], 0, 0, 0);
        }
    }

    // C/D layout: col=lane&15, row=(lane>>4)*4+reg (m89-verified)
#pragma unroll
    for (int jt = 0; jt < 4; ++jt) {
        int col = cb * 64 + 16 * jt + lm;
        float cz = causL[16 * jt + lm];
#pragma unroll
        for (int e = 0; e < 4; ++e) {
            int row = rb * 64 + 16 * w + q * 4 + e;
            out[(size_t)row * PDIM + col] = acc[jt][e] * cz;
        }
    }
}

// ---------------------------------------------------------------------------
extern "C" void kernel_launch(void* const* d_in, const int* in_sizes, int n_in,
                              void* d_out, int out_size, void* d_ws, size_t ws_size,
                              hipStream_t stream) {
    const float* u0  = (const float*)d_in[0];
    const float* xv  = (const float*)d_in[1];
    const float* tv  = (const float*)d_in[2];
    const float* bw1 = (const float*)d_in[3];
    const float* bb1 = (const float*)d_in[4];
    const float* bw2 = (const float*)d_in[5];
    const float* bb2 = (const float*)d_in[6];
    const float* bw3 = (const float*)d_in[7];
    const float* bb3 = (const float*)d_in[8];
    const float* tw1 = (const float*)d_in[9];
    const float* tb1 = (const float*)d_in[10];
    const float* tw2 = (const float*)d_in[11];
    const float* tb2 = (const float*)d_in[12];
    const float* tw3 = (const float*)d_in[13];
    const float* tb3 = (const float*)d_in[14];

    char* wsb = (char*)d_ws;
    __half* branch_out = (__half*)(wsb + WSB_BRANCH);
    __half* t3g        = (__half*)(wsb + WSB_T3);
    float* out = (float*)d_out;

    hipLaunchKernelGGL(k_mix, dim3(384), dim3(256), 0, stream,
                       u0, xv, tv, bw1, bb1, bw2, bb2, bw3, bb3,
                       tw1, tb1, tw2, tb2, tw3, tb3, branch_out, t3g);
    hipLaunchKernelGGL(k_final, dim3(256), dim3(256), 0, stream,
                       branch_out, t3g, xv, tv, out);
}